// Round 5
// baseline (1801.305 us; speedup 1.0000x reference)
//
#include <hip/hip_runtime.h>
#include <math.h>

#define DD 8192     // sketch dimension d
#define CC 768      // channels
#define SS 145      // sequence length
#define BB 32       // batch
#define SN 64       // sensor dim

// ---- kB geometry ----
#define CSLMAX 192  // max channels per slice (ns=4)

// ---- kD geometry ----
#define TN 128          // e-cols per block
#define NET (CC/TN)     // 6 e-tiles
#define CK 16           // c-chunk
#define LTS 164         // Lt row stride (mult of 4, b128-aligned)
#define NTD 320         // threads (5 waves): 20 s-groups x 16 e-groups
#define CHALF (CC/2)    // 384 channels per block (c-split x2)
#define NCHK (CHALF/CK) // 24 chunks
#define NWG (NET*BB*3*2)// 1152 blocks

// ---------------------------------------------------------------------------
// kB: per-(b,slice) partial Z vectors via LDS atomics (no global atomics).
//   Zuu[b,d]=sum u1[c]u2[e][h=d], Zcr[b,d]=sum (u1[c]s2[e]+s1[c]u2[e])[h=d],
//   Z11[d]  =sum s1[c]s2[e][h=d],  h=(h1[c]+h2[e])&(D-1),
//   u[b,c]=b_sen[c]+sum_n sensor[b,n]W_sen[c,n], u1=u*s1, u2=u*s2.
// ns = slices per b (runtime 8 or 4 depending on ws capacity).
// ---------------------------------------------------------------------------
__global__ __launch_bounds__(256) void kB(
    const float* __restrict__ sensor, const float* __restrict__ Wsen,
    const float* __restrict__ bsen,
    const int* __restrict__ h1, const int* __restrict__ h2,
    const int* __restrict__ s1, const int* __restrict__ s2,
    float* __restrict__ Zup, float* __restrict__ Zcp, float* __restrict__ Z1p,
    int ns)
{
    __shared__ float Za[DD], Zb[DD];              // 64 KB
    __shared__ float sens[SN];
    __shared__ float u2s[CC], s2f[CC];
    __shared__ int   h2s[CC];
    __shared__ float u1sl[CSLMAX], s1sl[CSLMAX];
    __shared__ int   h1sl[CSLMAX];

    const int sl  = blockIdx.x;
    const int b   = blockIdx.y;        // BB -> Z11 block
    const int tid = threadIdx.x;
    const bool z11 = (b == BB);
    const int csl = CC / ns;

    for (int d = tid; d < DD; d += 256) { Za[d] = 0.f; Zb[d] = 0.f; }
    if (!z11 && tid < SN) sens[tid] = sensor[b*SN + tid];
    __syncthreads();

    const int c0 = sl * csl;
    for (int c = tid; c < CC; c += 256) {
        float f2 = (float)s2[c];
        float u  = 0.f;
        if (!z11) {
            u = bsen[c];
            const float* w = Wsen + c*SN;
            #pragma unroll 8
            for (int n = 0; n < SN; ++n) u += sens[n] * w[n];
        }
        u2s[c] = u * f2; s2f[c] = f2; h2s[c] = h2[c];
        if (c >= c0 && c < c0 + csl) {
            float f1 = (float)s1[c];
            u1sl[c-c0] = u * f1; s1sl[c-c0] = f1; h1sl[c-c0] = h1[c];
        }
    }
    __syncthreads();

    float ue[3], se[3]; int he[3];
    #pragma unroll
    for (int k = 0; k < 3; ++k) {
        int e = tid + k*256;
        ue[k] = u2s[e]; se[k] = s2f[e]; he[k] = h2s[e];
    }

    if (z11) {
        for (int cc = 0; cc < csl; ++cc) {
            float s1c = s1sl[cc]; int h1c = h1sl[cc];
            #pragma unroll
            for (int k = 0; k < 3; ++k)
                atomicAdd(&Za[(h1c + he[k]) & (DD-1)], s1c * se[k]);
        }
    } else {
        for (int cc = 0; cc < csl; ++cc) {
            float u1c = u1sl[cc], s1c = s1sl[cc]; int h1c = h1sl[cc];
            #pragma unroll
            for (int k = 0; k < 3; ++k) {
                int ix = (h1c + he[k]) & (DD-1);
                atomicAdd(&Za[ix], u1c * ue[k]);
                atomicAdd(&Zb[ix], u1c * se[k] + s1c * ue[k]);
            }
        }
    }
    __syncthreads();

    if (z11) {
        float* da = Z1p + (size_t)sl*DD;
        for (int d = tid; d < DD; d += 256) da[d] = Za[d];
    } else {
        float* da = Zup + ((size_t)b*ns + sl)*DD;
        float* db = Zcp + ((size_t)b*ns + sl)*DD;
        for (int d = tid; d < DD; d += 256) { da[d] = Za[d]; db[d] = Zb[d]; }
    }
}

// ---------------------------------------------------------------------------
// kC: sum the ns partials into the final Zs[65][DD]:
//   a in [0,32): Zuu_b ; a in [32,64): Zcr_b ; a==64: Z11.
// ---------------------------------------------------------------------------
__global__ __launch_bounds__(256) void kC(
    const float* __restrict__ Zup, const float* __restrict__ Zcp,
    const float* __restrict__ Z1p, float* __restrict__ Zs, int ns)
{
    const int a  = blockIdx.y;
    const int d4 = blockIdx.x*256 + threadIdx.x;     // float4 index, DD/4=2048
    const float4* P = (const float4*)(
        (a < BB)      ? Zup + (size_t)a*ns*DD :
        (a < 2*BB)    ? Zcp + (size_t)(a-BB)*ns*DD : Z1p);
    float4 r = make_float4(0.f, 0.f, 0.f, 0.f);
    for (int j = 0; j < ns; ++j) {
        float4 v = P[(size_t)j*(DD/4) + d4];
        r.x += v.x; r.y += v.y; r.z += v.z; r.w += v.w;
    }
    ((float4*)(Zs + (size_t)a*DD))[d4] = r;
}

// ---------------------------------------------------------------------------
// kD: fused gather + dense quadratic forms, c-split x2, T14 reg-prefetch.
// 1D grid, XCD-swizzled -> (b, m, half, et). Per block: stage Zm (32 KB,
// L2-hot). Per c-chunk (CK=16): PREFETCH next chunk's E/s1/tok into regs
// (issued BEFORE the dense loop so HBM/L2 latency hides under FMAs);
// dense 8x8 register-tile FMAs on current Lt/Mt; barrier; write Lt from
// regs + gather Mt from Zm (pure LDS); barrier. fL/fR factor out of the
// bilinear form -> applied as one scale at the final atomicAdd:
//   m=0: w2^2*Zuu[b]  m=1: w2*bb*Zcr[b]  m=2: bb^2*Z11.
// LDS 52.5 KB -> 3 blocks/CU co-resident; grid 1152 -> ~4.5 blocks/CU queued.
// ---------------------------------------------------------------------------
__global__ __launch_bounds__(NTD) void kD(
    const float* __restrict__ E, const float* __restrict__ tok,
    const int* __restrict__ h1, const int* __restrict__ h2,
    const int* __restrict__ s1, const int* __restrict__ s2,
    const float* __restrict__ Ws2, const float* __restrict__ bs2,
    const float* __restrict__ Zs, float* __restrict__ Q)
{
    __shared__ __align__(16) float Zm[DD];          // 32768 B
    __shared__ __align__(16) float Lt[CK][LTS];     // 10496 B
    __shared__ __align__(16) float Mt[CK][TN];      //  8192 B
    __shared__ unsigned short h1u[CHALF];           //   768 B
    __shared__ unsigned short h2u[TN];              //   256 B
    // total 52480 B -> 3 blocks/CU

    // XCD swizzle: 1152 blocks, 144 per XCD -> 4 consecutive b per XCD
    const int bid = blockIdx.x;
    const int wg  = (bid & 7)*(NWG/8) + (bid >> 3);
    const int b   = wg / 36;
    const int r   = wg % 36;
    const int m   = r / 12;
    const int r2  = r % 12;
    const int half= r2 / 6;
    const int et  = r2 % 6;
    const int tid = threadIdx.x;
    const int e0  = et * TN;
    const int cb  = half * CHALF;

    // stage Zm (coalesced float4 from L2-resident summed Zs)
    {
        const float4* Zsrc = (const float4*)(Zs +
            (size_t)((m == 0) ? b : (m == 1) ? (BB + b) : 2*BB) * DD);
        float4* Zm4 = (float4*)Zm;
        for (int i = tid; i < DD/4; i += NTD) Zm4[i] = Zsrc[i];
    }
    for (int c = tid; c < CHALF; c += NTD) h1u[c] = (unsigned short)h1[cb + c];
    if (tid < TN) h2u[tid] = (unsigned short)h2[e0 + tid];
    __syncthreads();

    const int tc = tid & 15;          // e-col group
    const int tr = tid >> 4;          // s-row group (0..19)
    const int sBase = tr * 8;
    const int eA = tc * 4;            // low e half
    const int eB = 64 + tc * 4;       // high e half
    const int cL  = tid & 15;         // Lt staging: c within chunk
    const int sL0 = tid >> 4;         // Lt staging: s start (0..19)

    float pre[8], s1c, tt1;

#define PREFETCH(CKK) { \
    const int ca = cb + (CKK)*CK + cL; \
    s1c = (float)s1[ca]; \
    tt1 = tok[CC + ca]; \
    const float* ep = E + (size_t)b*SS*CC + ca; \
    _Pragma("unroll") \
    for (int k = 0; k < 8; ++k) { \
        int s = sL0 + 20*k; \
        pre[k] = (s < SS) ? ep[(size_t)s*CC] : 0.f; \
    } }

    // rows s>=SS hold garbage (t1s) but are never consumed (epilogue guards)
#define WRITE_LT { \
    float t1s = tt1 * s1c; \
    _Pragma("unroll") \
    for (int k = 0; k < 8; ++k) \
        Lt[cL][sL0 + 20*k] = pre[k]*s1c + t1s; \
    }

#define GATHER(CKK) { \
    const int cofs = (CKK)*CK; \
    for (int i = tid; i < CK*TN; i += NTD) { \
        int c = i >> 7, e = i & (TN-1); \
        Mt[c][e] = Zm[((int)h1u[cofs + c] + (int)h2u[e]) & (DD-1)]; \
    } }

    float acc[8][8];
    #pragma unroll
    for (int i = 0; i < 8; ++i)
        #pragma unroll
        for (int j = 0; j < 8; ++j) acc[i][j] = 0.f;

    // prologue: fill chunk 0
    PREFETCH(0)
    GATHER(0)
    WRITE_LT
    __syncthreads();

    for (int ck = 0; ck < NCHK; ++ck) {
        if (ck + 1 < NCHK) PREFETCH(ck + 1)      // issue loads, hide under dense

        // dense 8x8 outer-product accumulation on current chunk
        #pragma unroll
        for (int c = 0; c < CK; ++c) {
            float4 l0 = *(const float4*)&Lt[c][sBase];
            float4 l1 = *(const float4*)&Lt[c][sBase + 4];
            float4 m0 = *(const float4*)&Mt[c][eA];
            float4 m1 = *(const float4*)&Mt[c][eB];
            float lv[8] = {l0.x,l0.y,l0.z,l0.w,l1.x,l1.y,l1.z,l1.w};
            float mw[8] = {m0.x,m0.y,m0.z,m0.w,m1.x,m1.y,m1.z,m1.w};
            #pragma unroll
            for (int i = 0; i < 8; ++i)
                #pragma unroll
                for (int j = 0; j < 8; ++j)
                    acc[i][j] += lv[i] * mw[j];
        }
        __syncthreads();

        if (ck + 1 < NCHK) {
            GATHER(ck + 1)
            WRITE_LT
            __syncthreads();
        }
    }

    // --- epilogue: qv[s] = sum_j acc[i][j]*a2[s,e_j], reduce over tc,
    //     scale by fL*fR, atomicAdd ---
    const float4 tvA  = *(const float4*)&tok[CC + e0 + eA];
    const float4 tvB  = *(const float4*)&tok[CC + e0 + eB];
    const int4   sA   = *(const int4*)&s2[e0 + eA];
    const int4   sB   = *(const int4*)&s2[e0 + eB];
    const float sf[8] = {(float)sA.x,(float)sA.y,(float)sA.z,(float)sA.w,
                         (float)sB.x,(float)sB.y,(float)sB.z,(float)sB.w};
    const float tf[8] = {tvA.x*sf[0],tvA.y*sf[1],tvA.z*sf[2],tvA.w*sf[3],
                         tvB.x*sf[4],tvB.y*sf[5],tvB.z*sf[6],tvB.w*sf[7]};

    #pragma unroll
    for (int i = 0; i < 8; ++i) {
        int s = sBase + i;
        float qv = 0.f;
        if (s < SS) {
            const float* erow = E + ((size_t)b*SS + s)*CC + e0;
            const float4 evA = *(const float4*)&erow[eA];
            const float4 evB = *(const float4*)&erow[eB];
            float av[8] = {evA.x*sf[0]+tf[0], evA.y*sf[1]+tf[1],
                           evA.z*sf[2]+tf[2], evA.w*sf[3]+tf[3],
                           evB.x*sf[4]+tf[4], evB.y*sf[5]+tf[5],
                           evB.z*sf[6]+tf[6], evB.w*sf[7]+tf[7]};
            float t = 0.f;
            #pragma unroll
            for (int j = 0; j < 8; ++j) t += acc[i][j] * av[j];
            qv = t;
        }
        qv += __shfl_xor(qv, 1);
        qv += __shfl_xor(qv, 2);
        qv += __shfl_xor(qv, 4);
        qv += __shfl_xor(qv, 8);
        if (tc == 0 && s < SS) {
            float w2v = Ws2[s], bbv = bs2[s];
            float sc  = (m == 0) ? w2v*w2v : (m == 1) ? w2v*bbv : bbv*bbv;
            atomicAdd(&Q[b*SS + s], sc * qv);
        }
    }
#undef PREFETCH
#undef WRITE_LT
#undef GATHER
}

// ---------------------------------------------------------------------------
// kE: bp = sign(Q)*sqrt(|Q|+1e-5); L2-normalize over s; project W_out.
// ---------------------------------------------------------------------------
__global__ __launch_bounds__(256) void kE(
    const float* __restrict__ Q, const float* __restrict__ Wout,
    const float* __restrict__ bout, float* __restrict__ out)
{
    __shared__ float red[8];
    const int b = blockIdx.x, tid = threadIdx.x;
    float v = 0.f, w = 0.f;
    if (tid < SS) {
        float ip = Q[b*SS + tid];
        float sg = (ip > 0.f) ? 1.f : ((ip < 0.f) ? -1.f : 0.f);
        v = sg * sqrtf(fabsf(ip) + 1e-5f);
        w = v * Wout[tid];
    }
    float sq = v * v;
    #pragma unroll
    for (int off = 32; off > 0; off >>= 1) {
        sq += __shfl_down(sq, off, 64);
        w  += __shfl_down(w,  off, 64);
    }
    if ((tid & 63) == 0) { red[tid >> 6] = sq; red[4 + (tid >> 6)] = w; }
    __syncthreads();
    if (tid == 0) {
        float ssq  = red[0] + red[1] + red[2] + red[3];
        float sw   = red[4] + red[5] + red[6] + red[7];
        float norm = fmaxf(sqrtf(ssq), 1e-12f);
        out[b] = sw / norm + bout[0];
    }
}

// ---------------------------------------------------------------------------
extern "C" void kernel_launch(void* const* d_in, const int* in_sizes, int n_in,
                              void* d_out, int out_size, void* d_ws, size_t ws_size,
                              hipStream_t stream) {
    const float* sensor = (const float*)d_in[0];
    const float* E      = (const float*)d_in[1];
    const int*   h1     = (const int*)d_in[3];
    const int*   h2     = (const int*)d_in[4];
    const int*   s1     = (const int*)d_in[5];
    const int*   s2     = (const int*)d_in[6];
    const float* Wsen   = (const float*)d_in[8];
    const float* bsen   = (const float*)d_in[9];
    const float* Ws2    = (const float*)d_in[10];
    const float* bs2    = (const float*)d_in[11];
    const float* Wout   = (const float*)d_in[12];
    const float* bout   = (const float*)d_in[13];
    const float* tok    = (const float*)d_in[14];
    float* out = (float*)d_out;

    // ns=8 halves kB's per-block serial atomic chain; fall back to 4 if ws tight
    const size_t need8 = ((size_t)2*BB*8*DD + 8*DD + (size_t)(2*BB+1)*DD
                          + BB*SS) * sizeof(float);
    const int ns = (ws_size >= need8) ? 8 : 4;

    float* ws  = (float*)d_ws;
    float* Zup = ws;                               // BB*ns*DD
    float* Zcp = Zup + (size_t)BB*ns*DD;           // BB*ns*DD
    float* Z1p = Zcp + (size_t)BB*ns*DD;           // ns*DD
    float* Zs  = Z1p + (size_t)ns*DD;              // 65*DD (summed)
    float* Q   = Zs  + (size_t)(2*BB+1)*DD;        // BB*SS

    hipMemsetAsync(Q, 0, (size_t)BB*SS*sizeof(float), stream);

    kB<<<dim3(ns, BB+1), dim3(256), 0, stream>>>(
        sensor, Wsen, bsen, h1, h2, s1, s2, Zup, Zcp, Z1p, ns);

    kC<<<dim3(DD/4/256, 2*BB+1), dim3(256), 0, stream>>>(Zup, Zcp, Z1p, Zs, ns);

    kD<<<dim3(NWG), dim3(NTD), 0, stream>>>(
        E, tok, h1, h2, s1, s2, Ws2, bs2, Zs, Q);

    kE<<<dim3(BB), dim3(256), 0, stream>>>(Q, Wout, bout, out);
}

// Round 6
// 442.562 us; speedup vs baseline: 4.0702x; 4.0702x over previous
//
#include <hip/hip_runtime.h>
#include <hip/hip_bf16.h>
#include <math.h>

#define DD 8192     // sketch dimension d
#define CC 768      // channels
#define SS 145      // sequence length
#define BB 32       // batch
#define SN 64       // sensor dim

// ---- kB geometry ----
#define CSLMAX 192  // max channels per slice (ns=4)

// ---- kD geometry ----
#define TN 64            // e-cols per block
#define NET (CC/TN)      // 12 e-tiles
#define CK 64            // c per chunk
#define NCHK (CC/CK)     // 12 chunks
#define LTW 72           // Lt/Mt row stride in bf16 units (144 B, 16B-aligned)
#define NTD 512          // 8 waves
#define NWG (NET*BB*3)   // 1152 blocks

typedef __attribute__((ext_vector_type(8))) short short8;   // 8 bf16 (4 VGPR)
typedef __attribute__((ext_vector_type(4))) float f32x4;    // MFMA acc

// ---------------------------------------------------------------------------
// kB: per-(b,slice) partial Z vectors via LDS atomics (no global atomics).
//   Zuu[b,d]=sum u1[c]u2[e][h=d], Zcr[b,d]=sum (u1[c]s2[e]+s1[c]u2[e])[h=d],
//   Z11[d]  =sum s1[c]s2[e][h=d],  h=(h1[c]+h2[e])&(D-1),
//   u[b,c]=b_sen[c]+sum_n sensor[b,n]W_sen[c,n], u1=u*s1, u2=u*s2.
// ---------------------------------------------------------------------------
__global__ __launch_bounds__(256) void kB(
    const float* __restrict__ sensor, const float* __restrict__ Wsen,
    const float* __restrict__ bsen,
    const int* __restrict__ h1, const int* __restrict__ h2,
    const int* __restrict__ s1, const int* __restrict__ s2,
    float* __restrict__ Zup, float* __restrict__ Zcp, float* __restrict__ Z1p,
    int ns)
{
    __shared__ float Za[DD], Zb[DD];              // 64 KB
    __shared__ float sens[SN];
    __shared__ float u2s[CC], s2f[CC];
    __shared__ int   h2s[CC];
    __shared__ float u1sl[CSLMAX], s1sl[CSLMAX];
    __shared__ int   h1sl[CSLMAX];

    const int sl  = blockIdx.x;
    const int b   = blockIdx.y;        // BB -> Z11 block
    const int tid = threadIdx.x;
    const bool z11 = (b == BB);
    const int csl = CC / ns;

    for (int d = tid; d < DD; d += 256) { Za[d] = 0.f; Zb[d] = 0.f; }
    if (!z11 && tid < SN) sens[tid] = sensor[b*SN + tid];
    __syncthreads();

    const int c0 = sl * csl;
    for (int c = tid; c < CC; c += 256) {
        float f2 = (float)s2[c];
        float u  = 0.f;
        if (!z11) {
            u = bsen[c];
            const float* w = Wsen + c*SN;
            #pragma unroll 8
            for (int n = 0; n < SN; ++n) u += sens[n] * w[n];
        }
        u2s[c] = u * f2; s2f[c] = f2; h2s[c] = h2[c];
        if (c >= c0 && c < c0 + csl) {
            float f1 = (float)s1[c];
            u1sl[c-c0] = u * f1; s1sl[c-c0] = f1; h1sl[c-c0] = h1[c];
        }
    }
    __syncthreads();

    float ue[3], se[3]; int he[3];
    #pragma unroll
    for (int k = 0; k < 3; ++k) {
        int e = tid + k*256;
        ue[k] = u2s[e]; se[k] = s2f[e]; he[k] = h2s[e];
    }

    if (z11) {
        for (int cc = 0; cc < csl; ++cc) {
            float s1c = s1sl[cc]; int h1c = h1sl[cc];
            #pragma unroll
            for (int k = 0; k < 3; ++k)
                atomicAdd(&Za[(h1c + he[k]) & (DD-1)], s1c * se[k]);
        }
    } else {
        for (int cc = 0; cc < csl; ++cc) {
            float u1c = u1sl[cc], s1c = s1sl[cc]; int h1c = h1sl[cc];
            #pragma unroll
            for (int k = 0; k < 3; ++k) {
                int ix = (h1c + he[k]) & (DD-1);
                atomicAdd(&Za[ix], u1c * ue[k]);
                atomicAdd(&Zb[ix], u1c * se[k] + s1c * ue[k]);
            }
        }
    }
    __syncthreads();

    if (z11) {
        float* da = Z1p + (size_t)sl*DD;
        for (int d = tid; d < DD; d += 256) da[d] = Za[d];
    } else {
        float* da = Zup + ((size_t)b*ns + sl)*DD;
        float* db = Zcp + ((size_t)b*ns + sl)*DD;
        for (int d = tid; d < DD; d += 256) { da[d] = Za[d]; db[d] = Zb[d]; }
    }
}

// ---------------------------------------------------------------------------
// kC: sum the ns partials, convert to bf16 -> Zsb[65][DD]:
//   a in [0,32): Zuu_b ; a in [32,64): Zcr_b ; a==64: Z11.
// ---------------------------------------------------------------------------
__global__ __launch_bounds__(256) void kC(
    const float* __restrict__ Zup, const float* __restrict__ Zcp,
    const float* __restrict__ Z1p, __hip_bfloat16* __restrict__ Zsb, int ns)
{
    const int a  = blockIdx.y;
    const int d4 = blockIdx.x*256 + threadIdx.x;     // float4 index, DD/4=2048
    const float4* P = (const float4*)(
        (a < BB)      ? Zup + (size_t)a*ns*DD :
        (a < 2*BB)    ? Zcp + (size_t)(a-BB)*ns*DD : Z1p);
    float4 r = make_float4(0.f, 0.f, 0.f, 0.f);
    for (int j = 0; j < ns; ++j) {
        float4 v = P[(size_t)j*(DD/4) + d4];
        r.x += v.x; r.y += v.y; r.z += v.z; r.w += v.w;
    }
    __hip_bfloat16 o0 = __float2bfloat16(r.x), o1 = __float2bfloat16(r.y);
    __hip_bfloat16 o2 = __float2bfloat16(r.z), o3 = __float2bfloat16(r.w);
    unsigned int lo = (unsigned int)*(unsigned short*)&o0
                    | ((unsigned int)*(unsigned short*)&o1 << 16);
    unsigned int hi = (unsigned int)*(unsigned short*)&o2
                    | ((unsigned int)*(unsigned short*)&o3 << 16);
    uint2 pk; pk.x = lo; pk.y = hi;
    ((uint2*)(Zsb + (size_t)a*DD))[d4] = pk;
}

// ---------------------------------------------------------------------------
// kD: gather + bf16 MFMA quadratic forms.
// 1D grid, XCD-swizzled -> (b, m, et). Per block: stage Zm (16 KB bf16,
// L2-hot). Per c-chunk (CK=64): stage Lt[s][c]=bf16((E+tok1)*s1) and
// gathered Mt[e][c]=Zm[(h1c+h2e)&8191] (both row-stride 144 B); then 2
// K-steps of mfma_f32_16x16x32_bf16: wave w owns e-tile (w&3) and 5 s-tiles
// ((w>>2)*5..+4), acc 5 x f32x4. Epilogue contracts acc with a2 (fp32),
// shfl-reduces over 16 e-lanes, scales by the m-factor, atomicAdd into Q.
//   m=0: w2^2*Zuu[b]  m=1: w2*bb*Zcr[b]  m=2: bb^2*Z11.
// Fragment maps (m89/m91-verified): A row=l&15 k=(l>>4)*8+j; B col=l&15
// same k; C/D col=l&15 row=(l>>4)*4+reg.
// LDS 50.3 KB -> 3 blocks/CU (24 waves). launch_bounds(,1): no VGPR cap.
// ---------------------------------------------------------------------------
__global__ __launch_bounds__(NTD, 1) void kD(
    const float* __restrict__ E, const float* __restrict__ tok,
    const int* __restrict__ h1, const int* __restrict__ h2,
    const int* __restrict__ s1, const int* __restrict__ s2,
    const float* __restrict__ Ws2, const float* __restrict__ bs2,
    const __hip_bfloat16* __restrict__ Zsb, float* __restrict__ Q)
{
    __shared__ __align__(16) unsigned short Zm[DD];        // 16384 B
    __shared__ __align__(16) unsigned short Lt[160*LTW];   // 23040 B
    __shared__ __align__(16) unsigned short Mt[TN*LTW];    //  9216 B
    __shared__ unsigned short h1s[CC];                     //  1536 B
    __shared__ unsigned short h2s[TN];                     //   128 B
    // total ~50.3 KB -> 3 blocks/CU

    // XCD swizzle: 1152 blocks, 144 per XCD -> ~4 consecutive b per XCD
    const int bid = blockIdx.x;
    const int wg  = (bid & 7)*(NWG/8) + (bid >> 3);
    const int b   = wg / (3*NET);
    const int r   = wg % (3*NET);
    const int m   = r / NET;
    const int et  = r % NET;
    const int tid = threadIdx.x;
    const int e0  = et * TN;

    // stage Zm (bf16, coalesced uint4 from L2-resident Zsb)
    {
        const uint4* src = (const uint4*)(Zsb +
            (size_t)((m == 0) ? b : (m == 1) ? (BB + b) : 2*BB) * DD);
        uint4* dst = (uint4*)Zm;
        #pragma unroll
        for (int i = 0; i < 2; ++i) dst[tid + i*NTD] = src[tid + i*NTD]; // 1024 u4
    }
    for (int c = tid; c < CC; c += NTD) h1s[c] = (unsigned short)h1[c];
    if (tid < TN) h2s[tid] = (unsigned short)h2[e0 + tid];
    __syncthreads();

    const int lane = tid & 63;
    const int w    = tid >> 6;        // wave 0..7
    const int eT   = w & 3;           // e-tile within block
    const int sB   = (w >> 2) * 5;    // first s-tile
    const int l15  = lane & 15;
    const int l4   = lane >> 4;       // k-chunk / row-quad selector

    // staging maps
    const int c2 = tid & 31;          // c-pair (64 c per chunk)
    const int sL = tid >> 5;          // 0..15

    f32x4 acc[5];
    #pragma unroll
    for (int t = 0; t < 5; ++t) acc[t] = (f32x4){0.f, 0.f, 0.f, 0.f};

    for (int ck = 0; ck < NCHK; ++ck) {
        const int c0 = ck * CK;
        // --- stage Lt: 160 s x 64 c, bf16 pairs (coalesced float2 E reads) ---
        {
            const int c = c0 + 2*c2;
            const float s1a = (float)s1[c], s1b = (float)s1[c+1];
            const float ta = tok[CC + c] * s1a, tb = tok[CC + c + 1] * s1b;
            #pragma unroll
            for (int j = 0; j < 10; ++j) {
                int s = sL + 16*j;
                unsigned int word = 0;
                if (s < SS) {
                    const float2 ev = *(const float2*)&E[((size_t)b*SS + s)*CC + c];
                    __hip_bfloat16 x0 = __float2bfloat16(ev.x*s1a + ta);
                    __hip_bfloat16 x1 = __float2bfloat16(ev.y*s1b + tb);
                    word = (unsigned int)*(unsigned short*)&x0
                         | ((unsigned int)*(unsigned short*)&x1 << 16);
                }
                *(unsigned int*)&Lt[s*LTW + 2*c2] = word;
            }
        }
        // --- gather Mt: 64 e x 64 c from Zm (bf16 pass-through, no cvt) ---
        {
            const int hA = (int)h1s[c0 + 2*c2], hB = (int)h1s[c0 + 2*c2 + 1];
            #pragma unroll
            for (int j = 0; j < 4; ++j) {
                int e  = (tid >> 5) + 16*j;
                int he = (int)h2s[e];
                unsigned int lo = Zm[(hA + he) & (DD-1)];
                unsigned int hi = Zm[(hB + he) & (DD-1)];
                *(unsigned int*)&Mt[e*LTW + 2*c2] = lo | (hi << 16);
            }
        }
        __syncthreads();

        // --- MFMA: 2 K-steps of 32 over this chunk ---
        #pragma unroll
        for (int kk = 0; kk < 2; ++kk) {
            const int kb = kk*32 + l4*8;   // bf16 offset within row
            short8 bfrag = *(const short8*)&Mt[(eT*16 + l15)*LTW + kb];
            #pragma unroll
            for (int t = 0; t < 5; ++t) {
                short8 afrag = *(const short8*)&Lt[((sB + t)*16 + l15)*LTW + kb];
                acc[t] = __builtin_amdgcn_mfma_f32_16x16x32_bf16(
                    afrag, bfrag, acc[t], 0, 0, 0);
            }
        }
        __syncthreads();
    }

    // --- epilogue: q[s] = sum_e acc * a2[s,e]; reduce 16 e-lanes; scale; add ---
    const int   eg  = e0 + eT*16 + l15;
    const float s2e = (float)s2[eg];
    const float t2e = tok[CC + eg] * s2e;
    #pragma unroll
    for (int t = 0; t < 5; ++t) {
        #pragma unroll
        for (int rr = 0; rr < 4; ++rr) {
            int s = (sB + t)*16 + l4*4 + rr;
            float qv = 0.f;
            if (s < SS) {
                float a2v = E[((size_t)b*SS + s)*CC + eg] * s2e + t2e;
                qv = acc[t][rr] * a2v;
            }
            qv += __shfl_xor(qv, 1);
            qv += __shfl_xor(qv, 2);
            qv += __shfl_xor(qv, 4);
            qv += __shfl_xor(qv, 8);
            if (l15 == 0 && s < SS) {
                float w2v = Ws2[s], bbv = bs2[s];
                float sc  = (m == 0) ? w2v*w2v : (m == 1) ? w2v*bbv : bbv*bbv;
                atomicAdd(&Q[b*SS + s], sc * qv);
            }
        }
    }
}

// ---------------------------------------------------------------------------
// kE: bp = sign(Q)*sqrt(|Q|+1e-5); L2-normalize over s; project W_out.
// ---------------------------------------------------------------------------
__global__ __launch_bounds__(256) void kE(
    const float* __restrict__ Q, const float* __restrict__ Wout,
    const float* __restrict__ bout, float* __restrict__ out)
{
    __shared__ float red[8];
    const int b = blockIdx.x, tid = threadIdx.x;
    float v = 0.f, w = 0.f;
    if (tid < SS) {
        float ip = Q[b*SS + tid];
        float sg = (ip > 0.f) ? 1.f : ((ip < 0.f) ? -1.f : 0.f);
        v = sg * sqrtf(fabsf(ip) + 1e-5f);
        w = v * Wout[tid];
    }
    float sq = v * v;
    #pragma unroll
    for (int off = 32; off > 0; off >>= 1) {
        sq += __shfl_down(sq, off, 64);
        w  += __shfl_down(w,  off, 64);
    }
    if ((tid & 63) == 0) { red[tid >> 6] = sq; red[4 + (tid >> 6)] = w; }
    __syncthreads();
    if (tid == 0) {
        float ssq  = red[0] + red[1] + red[2] + red[3];
        float sw   = red[4] + red[5] + red[6] + red[7];
        float norm = fmaxf(sqrtf(ssq), 1e-12f);
        out[b] = sw / norm + bout[0];
    }
}

// ---------------------------------------------------------------------------
extern "C" void kernel_launch(void* const* d_in, const int* in_sizes, int n_in,
                              void* d_out, int out_size, void* d_ws, size_t ws_size,
                              hipStream_t stream) {
    const float* sensor = (const float*)d_in[0];
    const float* E      = (const float*)d_in[1];
    const int*   h1     = (const int*)d_in[3];
    const int*   h2     = (const int*)d_in[4];
    const int*   s1     = (const int*)d_in[5];
    const int*   s2     = (const int*)d_in[6];
    const float* Wsen   = (const float*)d_in[8];
    const float* bsen   = (const float*)d_in[9];
    const float* Ws2    = (const float*)d_in[10];
    const float* bs2    = (const float*)d_in[11];
    const float* Wout   = (const float*)d_in[12];
    const float* bout   = (const float*)d_in[13];
    const float* tok    = (const float*)d_in[14];
    float* out = (float*)d_out;

    // ns=8 halves kB's per-block serial atomic chain; fall back to 4 if ws tight
    const size_t need8 = ((size_t)2*BB*8*DD + 8*DD + BB*SS) * sizeof(float)
                         + (size_t)(2*BB+1)*DD * sizeof(__hip_bfloat16);
    const int ns = (ws_size >= need8) ? 8 : 4;

    float* ws  = (float*)d_ws;
    float* Zup = ws;                                    // BB*ns*DD f32
    float* Zcp = Zup + (size_t)BB*ns*DD;                // BB*ns*DD f32
    float* Z1p = Zcp + (size_t)BB*ns*DD;                // ns*DD f32
    __hip_bfloat16* Zsb = (__hip_bfloat16*)(Z1p + (size_t)ns*DD); // 65*DD bf16
    float* Q   = (float*)(Zsb + (size_t)(2*BB+1)*DD);   // BB*SS f32

    hipMemsetAsync(Q, 0, (size_t)BB*SS*sizeof(float), stream);

    kB<<<dim3(ns, BB+1), dim3(256), 0, stream>>>(
        sensor, Wsen, bsen, h1, h2, s1, s2, Zup, Zcp, Z1p, ns);

    kC<<<dim3(DD/4/256, 2*BB+1), dim3(256), 0, stream>>>(Zup, Zcp, Z1p, Zsb, ns);

    kD<<<dim3(NWG), dim3(NTD), 0, stream>>>(
        E, tok, h1, h2, s1, s2, Ws2, bs2, Zsb, Q);

    kE<<<dim3(BB), dim3(256), 0, stream>>>(Q, Wout, bout, out);
}

// Round 7
// 410.714 us; speedup vs baseline: 4.3858x; 1.0775x over previous
//
#include <hip/hip_runtime.h>
#include <hip/hip_bf16.h>
#include <math.h>

#define DD 8192     // sketch dimension d
#define CC 768      // channels
#define SS 145      // sequence length
#define BB 32       // batch
#define SN 64       // sensor dim

// ---- kB geometry ----
#define CSLMAX 192  // max channels per slice (ns=4 fallback)

// ---- kD geometry ----
#define TN 64            // e-cols per block
#define NET (CC/TN)      // 12 e-tiles
#define CK 64            // c per chunk
#define NCHK (CC/CK)     // 12 chunks
#define LTW 72           // Lt/Mt row stride in bf16 units (144 B, 16B-aligned)
#define NTD 512          // 8 waves
#define NWG (NET*BB*3)   // 1152 blocks

typedef __attribute__((ext_vector_type(8))) short short8;   // 8 bf16 (4 VGPR)
typedef __attribute__((ext_vector_type(4))) float f32x4;    // MFMA acc

// ---------------------------------------------------------------------------
// kB: per-(b,slice) partial Z vectors via NATIVE LDS atomics (ds_add_f32 via
// unsafeAtomicAdd — plain atomicAdd(float*) compiles to a CAS retry loop,
// ~300 cyc serialized per add; the native op is fire-and-forget).
//   Zuu[b,d]=sum u1[c]u2[e][h=d], Zcr[b,d]=sum (u1[c]s2[e]+s1[c]u2[e])[h=d],
//   Z11[d]  =sum s1[c]s2[e][h=d],  h=(h1[c]+h2[e])&(D-1),
//   u[b,c]=b_sen[c]+sum_n sensor[b,n]W_sen[c,n], u1=u*s1, u2=u*s2.
// ns slices per b (runtime 16/8/4 by ws capacity).
// ---------------------------------------------------------------------------
__global__ __launch_bounds__(256) void kB(
    const float* __restrict__ sensor, const float* __restrict__ Wsen,
    const float* __restrict__ bsen,
    const int* __restrict__ h1, const int* __restrict__ h2,
    const int* __restrict__ s1, const int* __restrict__ s2,
    float* __restrict__ Zup, float* __restrict__ Zcp, float* __restrict__ Z1p,
    int ns)
{
    __shared__ float Za[DD], Zb[DD];              // 64 KB
    __shared__ float sens[SN];
    __shared__ float u2s[CC], s2f[CC];
    __shared__ int   h2s[CC];
    __shared__ float u1sl[CSLMAX], s1sl[CSLMAX];
    __shared__ int   h1sl[CSLMAX];

    const int sl  = blockIdx.x;
    const int b   = blockIdx.y;        // BB -> Z11 block
    const int tid = threadIdx.x;
    const bool z11 = (b == BB);
    const int csl = CC / ns;

    for (int d = tid; d < DD; d += 256) { Za[d] = 0.f; Zb[d] = 0.f; }
    if (!z11 && tid < SN) sens[tid] = sensor[b*SN + tid];
    __syncthreads();

    const int c0 = sl * csl;
    for (int c = tid; c < CC; c += 256) {
        float f2 = (float)s2[c];
        float u  = 0.f;
        if (!z11) {
            u = bsen[c];
            const float* w = Wsen + c*SN;
            #pragma unroll 8
            for (int n = 0; n < SN; ++n) u += sens[n] * w[n];
        }
        u2s[c] = u * f2; s2f[c] = f2; h2s[c] = h2[c];
        if (c >= c0 && c < c0 + csl) {
            float f1 = (float)s1[c];
            u1sl[c-c0] = u * f1; s1sl[c-c0] = f1; h1sl[c-c0] = h1[c];
        }
    }
    __syncthreads();

    float ue[3], se[3]; int he[3];
    #pragma unroll
    for (int k = 0; k < 3; ++k) {
        int e = tid + k*256;
        ue[k] = u2s[e]; se[k] = s2f[e]; he[k] = h2s[e];
    }

    if (z11) {
        for (int cc = 0; cc < csl; ++cc) {
            float s1c = s1sl[cc]; int h1c = h1sl[cc];
            #pragma unroll
            for (int k = 0; k < 3; ++k)
                unsafeAtomicAdd(&Za[(h1c + he[k]) & (DD-1)], s1c * se[k]);
        }
    } else {
        for (int cc = 0; cc < csl; ++cc) {
            float u1c = u1sl[cc], s1c = s1sl[cc]; int h1c = h1sl[cc];
            #pragma unroll
            for (int k = 0; k < 3; ++k) {
                int ix = (h1c + he[k]) & (DD-1);
                unsafeAtomicAdd(&Za[ix], u1c * ue[k]);
                unsafeAtomicAdd(&Zb[ix], u1c * se[k] + s1c * ue[k]);
            }
        }
    }
    __syncthreads();

    if (z11) {
        float* da = Z1p + (size_t)sl*DD;
        for (int d = tid; d < DD; d += 256) da[d] = Za[d];
    } else {
        float* da = Zup + ((size_t)b*ns + sl)*DD;
        float* db = Zcp + ((size_t)b*ns + sl)*DD;
        for (int d = tid; d < DD; d += 256) { da[d] = Za[d]; db[d] = Zb[d]; }
    }
}

// ---------------------------------------------------------------------------
// kC: sum the ns partials, convert to bf16 -> Zsb[65][DD]:
//   a in [0,32): Zuu_b ; a in [32,64): Zcr_b ; a==64: Z11.
// ---------------------------------------------------------------------------
__global__ __launch_bounds__(256) void kC(
    const float* __restrict__ Zup, const float* __restrict__ Zcp,
    const float* __restrict__ Z1p, __hip_bfloat16* __restrict__ Zsb, int ns)
{
    const int a  = blockIdx.y;
    const int d4 = blockIdx.x*256 + threadIdx.x;     // float4 index, DD/4=2048
    const float4* P = (const float4*)(
        (a < BB)      ? Zup + (size_t)a*ns*DD :
        (a < 2*BB)    ? Zcp + (size_t)(a-BB)*ns*DD : Z1p);
    float4 r = make_float4(0.f, 0.f, 0.f, 0.f);
    for (int j = 0; j < ns; ++j) {
        float4 v = P[(size_t)j*(DD/4) + d4];
        r.x += v.x; r.y += v.y; r.z += v.z; r.w += v.w;
    }
    __hip_bfloat16 o0 = __float2bfloat16(r.x), o1 = __float2bfloat16(r.y);
    __hip_bfloat16 o2 = __float2bfloat16(r.z), o3 = __float2bfloat16(r.w);
    unsigned int lo = (unsigned int)*(unsigned short*)&o0
                    | ((unsigned int)*(unsigned short*)&o1 << 16);
    unsigned int hi = (unsigned int)*(unsigned short*)&o2
                    | ((unsigned int)*(unsigned short*)&o3 << 16);
    uint2 pk; pk.x = lo; pk.y = hi;
    ((uint2*)(Zsb + (size_t)a*DD))[d4] = pk;
}

// ---------------------------------------------------------------------------
// kD: gather + bf16 MFMA quadratic forms (unchanged from R5 except native
// global atomic in the epilogue).
// 1D grid, XCD-swizzled -> (b, m, et). Per block: stage Zm (16 KB bf16,
// L2-hot). Per c-chunk (CK=64): stage Lt[s][c]=bf16((E+tok1)*s1) and
// gathered Mt[e][c]=Zm[(h1c+h2e)&8191] (both row-stride 144 B); then 2
// K-steps of mfma_f32_16x16x32_bf16: wave w owns e-tile (w&3) and 5 s-tiles
// ((w>>2)*5..+4), acc 5 x f32x4. Epilogue contracts acc with a2 (fp32),
// shfl-reduces over 16 e-lanes, scales by the m-factor, atomicAdd into Q.
//   m=0: w2^2*Zuu[b]  m=1: w2*bb*Zcr[b]  m=2: bb^2*Z11.
// Fragment maps (m89/m91-verified): A row=l&15 k=(l>>4)*8+j; B col=l&15
// same k; C/D col=l&15 row=(l>>4)*4+reg.
// LDS 50.3 KB -> 3 blocks/CU (24 waves). launch_bounds(,1): no VGPR cap.
// ---------------------------------------------------------------------------
__global__ __launch_bounds__(NTD, 1) void kD(
    const float* __restrict__ E, const float* __restrict__ tok,
    const int* __restrict__ h1, const int* __restrict__ h2,
    const int* __restrict__ s1, const int* __restrict__ s2,
    const float* __restrict__ Ws2, const float* __restrict__ bs2,
    const __hip_bfloat16* __restrict__ Zsb, float* __restrict__ Q)
{
    __shared__ __align__(16) unsigned short Zm[DD];        // 16384 B
    __shared__ __align__(16) unsigned short Lt[160*LTW];   // 23040 B
    __shared__ __align__(16) unsigned short Mt[TN*LTW];    //  9216 B
    __shared__ unsigned short h1s[CC];                     //  1536 B
    __shared__ unsigned short h2s[TN];                     //   128 B
    // total ~50.3 KB -> 3 blocks/CU

    // XCD swizzle: 1152 blocks, 144 per XCD -> ~4 consecutive b per XCD
    const int bid = blockIdx.x;
    const int wg  = (bid & 7)*(NWG/8) + (bid >> 3);
    const int b   = wg / (3*NET);
    const int r   = wg % (3*NET);
    const int m   = r / NET;
    const int et  = r % NET;
    const int tid = threadIdx.x;
    const int e0  = et * TN;

    // stage Zm (bf16, coalesced uint4 from L2-resident Zsb)
    {
        const uint4* src = (const uint4*)(Zsb +
            (size_t)((m == 0) ? b : (m == 1) ? (BB + b) : 2*BB) * DD);
        uint4* dst = (uint4*)Zm;
        #pragma unroll
        for (int i = 0; i < 2; ++i) dst[tid + i*NTD] = src[tid + i*NTD]; // 1024 u4
    }
    for (int c = tid; c < CC; c += NTD) h1s[c] = (unsigned short)h1[c];
    if (tid < TN) h2s[tid] = (unsigned short)h2[e0 + tid];
    __syncthreads();

    const int lane = tid & 63;
    const int w    = tid >> 6;        // wave 0..7
    const int eT   = w & 3;           // e-tile within block
    const int sB   = (w >> 2) * 5;    // first s-tile
    const int l15  = lane & 15;
    const int l4   = lane >> 4;       // k-chunk / row-quad selector

    // staging maps
    const int c2 = tid & 31;          // c-pair (64 c per chunk)
    const int sL = tid >> 5;          // 0..15

    f32x4 acc[5];
    #pragma unroll
    for (int t = 0; t < 5; ++t) acc[t] = (f32x4){0.f, 0.f, 0.f, 0.f};

    for (int ck = 0; ck < NCHK; ++ck) {
        const int c0 = ck * CK;
        // --- stage Lt: 160 s x 64 c, bf16 pairs (coalesced float2 E reads) ---
        {
            const int c = c0 + 2*c2;
            const float s1a = (float)s1[c], s1b = (float)s1[c+1];
            const float ta = tok[CC + c] * s1a, tb = tok[CC + c + 1] * s1b;
            #pragma unroll
            for (int j = 0; j < 10; ++j) {
                int s = sL + 16*j;
                unsigned int word = 0;
                if (s < SS) {
                    const float2 ev = *(const float2*)&E[((size_t)b*SS + s)*CC + c];
                    __hip_bfloat16 x0 = __float2bfloat16(ev.x*s1a + ta);
                    __hip_bfloat16 x1 = __float2bfloat16(ev.y*s1b + tb);
                    word = (unsigned int)*(unsigned short*)&x0
                         | ((unsigned int)*(unsigned short*)&x1 << 16);
                }
                *(unsigned int*)&Lt[s*LTW + 2*c2] = word;
            }
        }
        // --- gather Mt: 64 e x 64 c from Zm (bf16 pass-through, no cvt) ---
        {
            const int hA = (int)h1s[c0 + 2*c2], hB = (int)h1s[c0 + 2*c2 + 1];
            #pragma unroll
            for (int j = 0; j < 4; ++j) {
                int e  = (tid >> 5) + 16*j;
                int he = (int)h2s[e];
                unsigned int lo = Zm[(hA + he) & (DD-1)];
                unsigned int hi = Zm[(hB + he) & (DD-1)];
                *(unsigned int*)&Mt[e*LTW + 2*c2] = lo | (hi << 16);
            }
        }
        __syncthreads();

        // --- MFMA: 2 K-steps of 32 over this chunk ---
        #pragma unroll
        for (int kk = 0; kk < 2; ++kk) {
            const int kb = kk*32 + l4*8;   // bf16 offset within row
            short8 bfrag = *(const short8*)&Mt[(eT*16 + l15)*LTW + kb];
            #pragma unroll
            for (int t = 0; t < 5; ++t) {
                short8 afrag = *(const short8*)&Lt[((sB + t)*16 + l15)*LTW + kb];
                acc[t] = __builtin_amdgcn_mfma_f32_16x16x32_bf16(
                    afrag, bfrag, acc[t], 0, 0, 0);
            }
        }
        __syncthreads();
    }

    // --- epilogue: q[s] = sum_e acc * a2[s,e]; reduce 16 e-lanes; scale; add ---
    const int   eg  = e0 + eT*16 + l15;
    const float s2e = (float)s2[eg];
    const float t2e = tok[CC + eg] * s2e;
    #pragma unroll
    for (int t = 0; t < 5; ++t) {
        #pragma unroll
        for (int rr = 0; rr < 4; ++rr) {
            int s = (sB + t)*16 + l4*4 + rr;
            float qv = 0.f;
            if (s < SS) {
                float a2v = E[((size_t)b*SS + s)*CC + eg] * s2e + t2e;
                qv = acc[t][rr] * a2v;
            }
            qv += __shfl_xor(qv, 1);
            qv += __shfl_xor(qv, 2);
            qv += __shfl_xor(qv, 4);
            qv += __shfl_xor(qv, 8);
            if (l15 == 0 && s < SS) {
                float w2v = Ws2[s], bbv = bs2[s];
                float sc  = (m == 0) ? w2v*w2v : (m == 1) ? w2v*bbv : bbv*bbv;
                unsafeAtomicAdd(&Q[b*SS + s], sc * qv);
            }
        }
    }
}

// ---------------------------------------------------------------------------
// kE: bp = sign(Q)*sqrt(|Q|+1e-5); L2-normalize over s; project W_out.
// ---------------------------------------------------------------------------
__global__ __launch_bounds__(256) void kE(
    const float* __restrict__ Q, const float* __restrict__ Wout,
    const float* __restrict__ bout, float* __restrict__ out)
{
    __shared__ float red[8];
    const int b = blockIdx.x, tid = threadIdx.x;
    float v = 0.f, w = 0.f;
    if (tid < SS) {
        float ip = Q[b*SS + tid];
        float sg = (ip > 0.f) ? 1.f : ((ip < 0.f) ? -1.f : 0.f);
        v = sg * sqrtf(fabsf(ip) + 1e-5f);
        w = v * Wout[tid];
    }
    float sq = v * v;
    #pragma unroll
    for (int off = 32; off > 0; off >>= 1) {
        sq += __shfl_down(sq, off, 64);
        w  += __shfl_down(w,  off, 64);
    }
    if ((tid & 63) == 0) { red[tid >> 6] = sq; red[4 + (tid >> 6)] = w; }
    __syncthreads();
    if (tid == 0) {
        float ssq  = red[0] + red[1] + red[2] + red[3];
        float sw   = red[4] + red[5] + red[6] + red[7];
        float norm = fmaxf(sqrtf(ssq), 1e-12f);
        out[b] = sw / norm + bout[0];
    }
}

// ---------------------------------------------------------------------------
extern "C" void kernel_launch(void* const* d_in, const int* in_sizes, int n_in,
                              void* d_out, int out_size, void* d_ws, size_t ws_size,
                              hipStream_t stream) {
    const float* sensor = (const float*)d_in[0];
    const float* E      = (const float*)d_in[1];
    const int*   h1     = (const int*)d_in[3];
    const int*   h2     = (const int*)d_in[4];
    const int*   s1     = (const int*)d_in[5];
    const int*   s2     = (const int*)d_in[6];
    const float* Wsen   = (const float*)d_in[8];
    const float* bsen   = (const float*)d_in[9];
    const float* Ws2    = (const float*)d_in[10];
    const float* bs2    = (const float*)d_in[11];
    const float* Wout   = (const float*)d_in[12];
    const float* bout   = (const float*)d_in[13];
    const float* tok    = (const float*)d_in[14];
    float* out = (float*)d_out;

    // ns slices per b: more slices = shorter per-block atomic chain + more
    // blocks. Pick largest that fits the workspace.
    auto need = [](int ns_) {
        return ((size_t)2*BB*ns_*DD + ns_*DD + BB*SS) * sizeof(float)
               + (size_t)(2*BB+1)*DD * sizeof(__hip_bfloat16);
    };
    const int ns = (ws_size >= need(16)) ? 16 : (ws_size >= need(8)) ? 8 : 4;

    float* ws  = (float*)d_ws;
    float* Zup = ws;                                    // BB*ns*DD f32
    float* Zcp = Zup + (size_t)BB*ns*DD;                // BB*ns*DD f32
    float* Z1p = Zcp + (size_t)BB*ns*DD;                // ns*DD f32
    __hip_bfloat16* Zsb = (__hip_bfloat16*)(Z1p + (size_t)ns*DD); // 65*DD bf16
    float* Q   = (float*)(Zsb + (size_t)(2*BB+1)*DD);   // BB*SS f32

    hipMemsetAsync(Q, 0, (size_t)BB*SS*sizeof(float), stream);

    kB<<<dim3(ns, BB+1), dim3(256), 0, stream>>>(
        sensor, Wsen, bsen, h1, h2, s1, s2, Zup, Zcp, Z1p, ns);

    kC<<<dim3(DD/4/256, 2*BB+1), dim3(256), 0, stream>>>(Zup, Zcp, Z1p, Zsb, ns);

    kD<<<dim3(NWG), dim3(NTD), 0, stream>>>(
        E, tok, h1, h2, s1, s2, Ws2, bs2, Zsb, Q);

    kE<<<dim3(BB), dim3(256), 0, stream>>>(Q, Wout, bout, out);
}

// Round 8
// 223.153 us; speedup vs baseline: 8.0721x; 1.8405x over previous
//
#include <hip/hip_runtime.h>
#include <hip/hip_bf16.h>
#include <math.h>

#define DD 8192     // sketch dimension d
#define CC 768      // channels
#define SS 145      // sequence length
#define BB 32       // batch
#define SN 64       // sensor dim

// ---- kD geometry (unchanged from R6) ----
#define TN 64            // e-cols per block
#define NET (CC/TN)      // 12 e-tiles
#define CK 64            // c per chunk
#define NCHK (CC/CK)     // 12 chunks
#define LTW 72           // Lt/Mt row stride in bf16 units (144 B, 16B-aligned)
#define NTD 512          // 8 waves
#define NWG (NET*BB*3)   // 1152 blocks

// ---- kZ geometry ----
#define ZT 512           // threads
#define NSL 16           // d-slices per b -> 512 blocks

typedef __attribute__((ext_vector_type(8))) short short8;   // 8 bf16 (4 VGPR)
typedef __attribute__((ext_vector_type(4))) float f32x4;    // MFMA acc

// ---------------------------------------------------------------------------
// kS: per-b sketch build. Computes u[b,c] = b_sen[c] + sensor[b,:]·Wsen[c,:],
// writes CTG[b][c] = (u1=u*s1, s1, bits(h1c), 0) for kZ's uniform loads, and
// scatters the e-side sketches into LDS then out to P2G[b][t] =
// (S2u_b[t], S2s[t]) with S2u_b[t]=sum_{h2e=t} u[e]*s2[e], S2s[t]=sum s2[e].
// Only 2*768 LDS atomics per block (vs 38M in the old kB).
// ---------------------------------------------------------------------------
__global__ __launch_bounds__(512) void kS(
    const float* __restrict__ sensor, const float* __restrict__ Wsen,
    const float* __restrict__ bsen,
    const int* __restrict__ h1, const int* __restrict__ h2,
    const int* __restrict__ s1, const int* __restrict__ s2,
    float4* __restrict__ CTG, float2* __restrict__ P2G)
{
    __shared__ float2 P2l[DD];        // 64 KB
    __shared__ float  sens[SN];
    const int b   = blockIdx.x;
    const int tid = threadIdx.x;

    if (tid < SN) sens[tid] = sensor[b*SN + tid];
    {
        float4* p4 = (float4*)P2l;
        #pragma unroll
        for (int i = 0; i < 8; ++i) p4[tid + i*512] = make_float4(0.f,0.f,0.f,0.f);
    }
    __syncthreads();

    for (int c = tid; c < CC; c += 512) {
        float u = bsen[c];
        const float4* w = (const float4*)(Wsen + (size_t)c*SN);
        #pragma unroll
        for (int n4 = 0; n4 < 16; ++n4) {
            float4 wv = w[n4];
            u += sens[4*n4+0]*wv.x + sens[4*n4+1]*wv.y
               + sens[4*n4+2]*wv.z + sens[4*n4+3]*wv.w;
        }
        float f1 = (float)s1[c], f2 = (float)s2[c];
        float4 ct;
        ct.x = u * f1; ct.y = f1; ct.z = __int_as_float(h1[c]); ct.w = 0.f;
        CTG[(size_t)b*CC + c] = ct;
        int t = h2[c];
        unsafeAtomicAdd(&P2l[t].x, u * f2);
        unsafeAtomicAdd(&P2l[t].y, f2);
    }
    __syncthreads();

    {
        const float4* p4 = (const float4*)P2l;
        float4* dst = (float4*)(P2G + (size_t)b*DD);
        #pragma unroll
        for (int i = 0; i < 8; ++i) dst[tid + i*512] = p4[tid + i*512];
    }
}

// ---------------------------------------------------------------------------
// kZ: gather-free Z build via shifted-sketch sums.
//   Zuu_b[d] = sum_c u1[c]*S2u_b[(d-h1c)&8191]
//   Zcr_b[d] = sum_c u1[c]*S2s[(d-h1c)] + s1[c]*S2u_b[(d-h1c)]
//   Z11[d]   = sum_c s1[c]*S2s[(d-h1c)]        (written by b==0 blocks)
// One thread owns one d. P2 (interleaved float2) staged in LDS: the inner-
// loop read is unit-stride-across-lanes b64 -> conflict-free. c-scalars are
// loop-uniform global reads (s_load path). Writes bf16 Zsb directly (kC
// deleted). Grid 512 = (b, dslice), XCD-swizzled so all slices of a b share
// an XCD's L2 copy of P2G[b].
// ---------------------------------------------------------------------------
__global__ __launch_bounds__(ZT) void kZ(
    const float4* __restrict__ CTG, const float2* __restrict__ P2G,
    __hip_bfloat16* __restrict__ Zsb)
{
    __shared__ float2 P2l[DD];        // 64 KB -> 2 blocks/CU

    const int bid = blockIdx.x;
    const int wg  = (bid & 7)*(BB*NSL/8) + (bid >> 3);
    const int b   = wg >> 4;
    const int dsl = wg & (NSL-1);
    const int tid = threadIdx.x;

    {
        const float4* src = (const float4*)(P2G + (size_t)b*DD);
        float4* dst = (float4*)P2l;
        #pragma unroll
        for (int i = 0; i < 8; ++i) dst[tid + i*ZT] = src[tid + i*ZT];
    }
    __syncthreads();

    const int d = dsl*ZT + tid;
    const float4* ctp = CTG + (size_t)b*CC;
    float accU = 0.f, accC = 0.f, acc1 = 0.f;
    #pragma unroll 4
    for (int c = 0; c < CC; ++c) {
        float4 ct = ctp[c];                       // uniform -> s_load_dwordx4
        int idx = (d - __float_as_int(ct.z)) & (DD-1);
        float2 p = P2l[idx];                      // conflict-free b64 gather
        accU = fmaf(ct.x, p.x, accU);
        accC = fmaf(ct.x, p.y, fmaf(ct.y, p.x, accC));
        acc1 = fmaf(ct.y, p.y, acc1);
    }

    Zsb[(size_t)b*DD + d]        = __float2bfloat16(accU);
    Zsb[(size_t)(BB + b)*DD + d] = __float2bfloat16(accC);
    if (b == 0) Zsb[(size_t)2*BB*DD + d] = __float2bfloat16(acc1);
}

// ---------------------------------------------------------------------------
// kD: gather + bf16 MFMA quadratic forms (unchanged from R6).
// 1D grid, XCD-swizzled -> (b, m, et). Per block: stage Zm (16 KB bf16,
// L2-hot). Per c-chunk (CK=64): stage Lt[s][c]=bf16((E+tok1)*s1) and
// gathered Mt[e][c]=Zm[(h1c+h2e)&8191]; then 2 K-steps of
// mfma_f32_16x16x32_bf16: wave w owns e-tile (w&3) and 5 s-tiles, acc 5 x
// f32x4. Epilogue contracts acc with a2 (fp32), shfl-reduces over 16
// e-lanes, scales by the m-factor, atomicAdd into Q.
//   m=0: w2^2*Zuu[b]  m=1: w2*bb*Zcr[b]  m=2: bb^2*Z11.
// ---------------------------------------------------------------------------
__global__ __launch_bounds__(NTD, 1) void kD(
    const float* __restrict__ E, const float* __restrict__ tok,
    const int* __restrict__ h1, const int* __restrict__ h2,
    const int* __restrict__ s1, const int* __restrict__ s2,
    const float* __restrict__ Ws2, const float* __restrict__ bs2,
    const __hip_bfloat16* __restrict__ Zsb, float* __restrict__ Q)
{
    __shared__ __align__(16) unsigned short Zm[DD];        // 16384 B
    __shared__ __align__(16) unsigned short Lt[160*LTW];   // 23040 B
    __shared__ __align__(16) unsigned short Mt[TN*LTW];    //  9216 B
    __shared__ unsigned short h1s[CC];                     //  1536 B
    __shared__ unsigned short h2s[TN];                     //   128 B

    const int bid = blockIdx.x;
    const int wg  = (bid & 7)*(NWG/8) + (bid >> 3);
    const int b   = wg / (3*NET);
    const int r   = wg % (3*NET);
    const int m   = r / NET;
    const int et  = r % NET;
    const int tid = threadIdx.x;
    const int e0  = et * TN;

    {
        const uint4* src = (const uint4*)(Zsb +
            (size_t)((m == 0) ? b : (m == 1) ? (BB + b) : 2*BB) * DD);
        uint4* dst = (uint4*)Zm;
        #pragma unroll
        for (int i = 0; i < 2; ++i) dst[tid + i*NTD] = src[tid + i*NTD];
    }
    for (int c = tid; c < CC; c += NTD) h1s[c] = (unsigned short)h1[c];
    if (tid < TN) h2s[tid] = (unsigned short)h2[e0 + tid];
    __syncthreads();

    const int lane = tid & 63;
    const int w    = tid >> 6;
    const int eT   = w & 3;
    const int sB   = (w >> 2) * 5;
    const int l15  = lane & 15;
    const int l4   = lane >> 4;
    const int c2 = tid & 31;
    const int sL = tid >> 5;

    f32x4 acc[5];
    #pragma unroll
    for (int t = 0; t < 5; ++t) acc[t] = (f32x4){0.f, 0.f, 0.f, 0.f};

    for (int ck = 0; ck < NCHK; ++ck) {
        const int c0 = ck * CK;
        {
            const int c = c0 + 2*c2;
            const float s1a = (float)s1[c], s1b = (float)s1[c+1];
            const float ta = tok[CC + c] * s1a, tb = tok[CC + c + 1] * s1b;
            #pragma unroll
            for (int j = 0; j < 10; ++j) {
                int s = sL + 16*j;
                unsigned int word = 0;
                if (s < SS) {
                    const float2 ev = *(const float2*)&E[((size_t)b*SS + s)*CC + c];
                    __hip_bfloat16 x0 = __float2bfloat16(ev.x*s1a + ta);
                    __hip_bfloat16 x1 = __float2bfloat16(ev.y*s1b + tb);
                    word = (unsigned int)*(unsigned short*)&x0
                         | ((unsigned int)*(unsigned short*)&x1 << 16);
                }
                *(unsigned int*)&Lt[s*LTW + 2*c2] = word;
            }
        }
        {
            const int hA = (int)h1s[c0 + 2*c2], hB = (int)h1s[c0 + 2*c2 + 1];
            #pragma unroll
            for (int j = 0; j < 4; ++j) {
                int e  = (tid >> 5) + 16*j;
                int he = (int)h2s[e];
                unsigned int lo = Zm[(hA + he) & (DD-1)];
                unsigned int hi = Zm[(hB + he) & (DD-1)];
                *(unsigned int*)&Mt[e*LTW + 2*c2] = lo | (hi << 16);
            }
        }
        __syncthreads();

        #pragma unroll
        for (int kk = 0; kk < 2; ++kk) {
            const int kb = kk*32 + l4*8;
            short8 bfrag = *(const short8*)&Mt[(eT*16 + l15)*LTW + kb];
            #pragma unroll
            for (int t = 0; t < 5; ++t) {
                short8 afrag = *(const short8*)&Lt[((sB + t)*16 + l15)*LTW + kb];
                acc[t] = __builtin_amdgcn_mfma_f32_16x16x32_bf16(
                    afrag, bfrag, acc[t], 0, 0, 0);
            }
        }
        __syncthreads();
    }

    const int   eg  = e0 + eT*16 + l15;
    const float s2e = (float)s2[eg];
    const float t2e = tok[CC + eg] * s2e;
    #pragma unroll
    for (int t = 0; t < 5; ++t) {
        #pragma unroll
        for (int rr = 0; rr < 4; ++rr) {
            int s = (sB + t)*16 + l4*4 + rr;
            float qv = 0.f;
            if (s < SS) {
                float a2v = E[((size_t)b*SS + s)*CC + eg] * s2e + t2e;
                qv = acc[t][rr] * a2v;
            }
            qv += __shfl_xor(qv, 1);
            qv += __shfl_xor(qv, 2);
            qv += __shfl_xor(qv, 4);
            qv += __shfl_xor(qv, 8);
            if (l15 == 0 && s < SS) {
                float w2v = Ws2[s], bbv = bs2[s];
                float sc  = (m == 0) ? w2v*w2v : (m == 1) ? w2v*bbv : bbv*bbv;
                unsafeAtomicAdd(&Q[b*SS + s], sc * qv);
            }
        }
    }
}

// ---------------------------------------------------------------------------
// kE: bp = sign(Q)*sqrt(|Q|+1e-5); L2-normalize over s; project W_out.
// ---------------------------------------------------------------------------
__global__ __launch_bounds__(256) void kE(
    const float* __restrict__ Q, const float* __restrict__ Wout,
    const float* __restrict__ bout, float* __restrict__ out)
{
    __shared__ float red[8];
    const int b = blockIdx.x, tid = threadIdx.x;
    float v = 0.f, w = 0.f;
    if (tid < SS) {
        float ip = Q[b*SS + tid];
        float sg = (ip > 0.f) ? 1.f : ((ip < 0.f) ? -1.f : 0.f);
        v = sg * sqrtf(fabsf(ip) + 1e-5f);
        w = v * Wout[tid];
    }
    float sq = v * v;
    #pragma unroll
    for (int off = 32; off > 0; off >>= 1) {
        sq += __shfl_down(sq, off, 64);
        w  += __shfl_down(w,  off, 64);
    }
    if ((tid & 63) == 0) { red[tid >> 6] = sq; red[4 + (tid >> 6)] = w; }
    __syncthreads();
    if (tid == 0) {
        float ssq  = red[0] + red[1] + red[2] + red[3];
        float sw   = red[4] + red[5] + red[6] + red[7];
        float norm = fmaxf(sqrtf(ssq), 1e-12f);
        out[b] = sw / norm + bout[0];
    }
}

// ---------------------------------------------------------------------------
extern "C" void kernel_launch(void* const* d_in, const int* in_sizes, int n_in,
                              void* d_out, int out_size, void* d_ws, size_t ws_size,
                              hipStream_t stream) {
    const float* sensor = (const float*)d_in[0];
    const float* E      = (const float*)d_in[1];
    const int*   h1     = (const int*)d_in[3];
    const int*   h2     = (const int*)d_in[4];
    const int*   s1     = (const int*)d_in[5];
    const int*   s2     = (const int*)d_in[6];
    const float* Wsen   = (const float*)d_in[8];
    const float* bsen   = (const float*)d_in[9];
    const float* Ws2    = (const float*)d_in[10];
    const float* bs2    = (const float*)d_in[11];
    const float* Wout   = (const float*)d_in[12];
    const float* bout   = (const float*)d_in[13];
    const float* tok    = (const float*)d_in[14];
    float* out = (float*)d_out;

    // workspace layout (16B-aligned sections, ~3.6 MB total)
    char* ws = (char*)d_ws;
    float4* CTG = (float4*)ws;                                  // 32*768*16 B
    float2* P2G = (float2*)(ws + (size_t)BB*CC*16);             // 32*8192*8 B
    __hip_bfloat16* Zsb = (__hip_bfloat16*)(ws + (size_t)BB*CC*16
                          + (size_t)BB*DD*8);                   // 65*8192*2 B
    float* Q = (float*)((char*)Zsb + (size_t)(2*BB+1)*DD*2);    // 32*145*4 B

    hipMemsetAsync(Q, 0, (size_t)BB*SS*sizeof(float), stream);

    kS<<<dim3(BB), dim3(512), 0, stream>>>(
        sensor, Wsen, bsen, h1, h2, s1, s2, CTG, P2G);

    kZ<<<dim3(BB*NSL), dim3(ZT), 0, stream>>>(CTG, P2G, Zsb);

    kD<<<dim3(NWG), dim3(NTD), 0, stream>>>(
        E, tok, h1, h2, s1, s2, Ws2, bs2, Zsb, Q);

    kE<<<dim3(BB), dim3(256), 0, stream>>>(Q, Wout, bout, out);
}